// Round 11
// baseline (4704.565 us; speedup 1.0000x reference)
//
#include <hip/hip_runtime.h>
#include <math.h>

// Decoder_82231443849250: persistent-kernel recurrent MLP decoder. Round 11.
// = Round-10 pipeline, restructured as a TWO-HALF TEMPORAL INTERLEAVE:
//   each XCD-group's 32 batch rows split into independent halves A (rows
//   0-15) and B (rows 16-31), each with its own slot-barrier array. Phases
//   alternate A/B so every barrier's settle hides under the other half's
//   compute: arrive(A); wait(B); phase(B); arrive(B); wait(A); phase(A)...
// Barrier mechanics = r10-proven xbar2 pieces: arrival = relaxed agent-scope
// atomic fetch_add on own 64B slot; poll = wave0 per-lane sc0 sc1 load +
// __all; data reads = sc0 (fresh-by-L1-eviction: >=130KB streams through the
// 32KB L1 between same-address rereads). All spins carry bailouts.

#define NB 256
#define NS 128
#define NH 1024
#define NJ 12
#define NPIN 139
#define NPD 42
#define WPG 32
#define BROW 32
#define W2S 1032
#define AS 1032

typedef __attribute__((ext_vector_type(8))) short short8;
typedef __attribute__((ext_vector_type(4))) float f32x4;
typedef __attribute__((ext_vector_type(2))) float f32x2;

struct Params {
  const float* z; const float* obs; const float* W1; const float* b1;
  const float* g1; const float* be1; const float* W2; const float* b2;
  const float* g2; const float* be2; const float* Wa1; const float* ba1;
  const float* Wa2; const float* ba2; const float* Wo; const float* bo;
  const float* Wv; const float* bv; const float* alog; const float* fkW;
  const float* fkb; const float* pmean; const float* pstd; const float* jlo;
  const float* jhi; const float* ddp;
  float* out_gmu; float* out_joint; float* out_act; float* out_ls;
  float* zc; float* pa; float* part1; float* part2;
  unsigned short* y1b; unsigned short* y2b;
  unsigned short* wa1b; unsigned short* wexb;
  unsigned int* gcnt; unsigned int* slots;
};

__device__ __forceinline__ unsigned short f2bf(float x) {
  union { float f; unsigned u; } v; v.f = x;
  unsigned r = v.u + 0x7FFFu + ((v.u >> 16) & 1u);
  return (unsigned short)(r >> 16);
}
__device__ __forceinline__ float bf2f(unsigned short x) {
  union { unsigned u; float f; } v; v.u = ((unsigned)x) << 16;
  return v.f;
}
__device__ __forceinline__ unsigned cvt_pk_bf16(float lo, float hi) {
  unsigned r;
  asm("v_cvt_pk_bf16_f32 %0, %1, %2" : "=v"(r) : "v"(lo), "v"(hi));
  return r;
}
__device__ __forceinline__ void ld16_sc0(const unsigned short* p, short8& d) {
  asm volatile("global_load_dwordx4 %0, %1, off sc0" : "=v"(d) : "v"(p));
}
__device__ __forceinline__ void ldf4_sc0(const float* p, f32x4& d) {
  asm volatile("global_load_dwordx4 %0, %1, off sc0" : "=v"(d) : "v"(p));
}
__device__ __forceinline__ void vwait0() {
  asm volatile("s_waitcnt vmcnt(0)" ::: "memory");
  __builtin_amdgcn_sched_barrier(0);  // rule #18: pin uses after the wait
}

__device__ __forceinline__ f32x4 dot1024(const unsigned short* a, const unsigned short* b) {
  const short8* ap = (const short8*)a;
  const short8* bp = (const short8*)b;
  f32x4 acc0 = {0.f, 0.f, 0.f, 0.f};
  f32x4 acc1 = {0.f, 0.f, 0.f, 0.f};
#pragma unroll 4
  for (int k8 = 0; k8 < 128; k8 += 8) {
    acc0 = __builtin_amdgcn_mfma_f32_16x16x32_bf16(ap[k8], bp[k8], acc0, 0, 0, 0);
    acc1 = __builtin_amdgcn_mfma_f32_16x16x32_bf16(ap[k8 + 4], bp[k8 + 4], acc1, 0, 0, 0);
  }
  return acc0 + acc1;
}

// ---- one-time global barrier (cross-XCD safe): full fences, used once.
__device__ __forceinline__ void gbar(unsigned int* c, unsigned int target) {
  __threadfence();
  __syncthreads();
  if (threadIdx.x == 0) {
    __hip_atomic_fetch_add(c, 1u, __ATOMIC_RELEASE, __HIP_MEMORY_SCOPE_AGENT);
    unsigned long long t0 = __builtin_amdgcn_s_memrealtime();
    while (__hip_atomic_load(c, __ATOMIC_ACQUIRE, __HIP_MEMORY_SCOPE_AGENT) < target) {
      __builtin_amdgcn_s_sleep(16);
      if (__builtin_amdgcn_s_memrealtime() - t0 > (1ull << 25)) break;
    }
  }
  __syncthreads();
  __threadfence();
}

// ---- slot-wait: wave 0 polls all 32 slots (sc0 sc1 -> coherence point).
__device__ __forceinline__ void slot_wait(const unsigned int* sg, unsigned target, int lane) {
  const unsigned int* myslot = sg + (size_t)(lane & 31) * 16;
  unsigned long long t0 = __builtin_amdgcn_s_memrealtime();
  for (;;) {
    unsigned v;
    asm volatile("global_load_dword %0, %1, off sc0 sc1\n\t"
                 "s_waitcnt vmcnt(0)"
                 : "=v"(v) : "v"(myslot) : "memory");
    if (__all(v >= target)) break;
    __builtin_amdgcn_s_sleep(1);
    if (__builtin_amdgcn_s_memrealtime() - t0 > (1ull << 23)) break;  // bail, never hang
  }
}
// arrive: drain data stores, sync all waves, one uncontended atomic.
__device__ __forceinline__ void arrive_bar(unsigned int* myslot, int tid) {
  asm volatile("s_waitcnt vmcnt(0)" ::: "memory");
  __syncthreads();
  if (tid == 0)
    __hip_atomic_fetch_add(myslot, 1u, __ATOMIC_RELAXED, __HIP_MEMORY_SCOPE_AGENT);
}
__device__ __forceinline__ void wait_bar(const unsigned int* sg, unsigned target,
                                         int wave, int lane) {
  if (wave == 0) slot_wait(sg, target, lane);
  __syncthreads();
}

__global__ __launch_bounds__(256, 1) void decoder_persistent(Params p) {
  __shared__ unsigned short w2l[BROW * W2S];    // 66 KB: W2 col-slice bf16
  __shared__ unsigned short albuf[16 * AS];     // 33 KB: normalized A (one half)
  __shared__ float g1l[NH], be1l[NH], g2l[NH], be2l[NH];  // 16 KB
  __shared__ unsigned short t1l[16 * 40];
  __shared__ unsigned short wa2l[16 * 40];
  __shared__ float pjA[16 * NJ], pdqA[16 * NJ], pjB[16 * NJ], pdqB[16 * NJ];
  __shared__ float alpha_l[NJ], jm_l[NJ], jri_l[NJ], lo_l[NJ], hi_l[NJ], ddp_l[NJ], ba2_l[NJ];
  __shared__ float pm_l[NPD], psi_l[NPD], bv_l[NPD], bo_l[4];

  const int tid = threadIdx.x;
  const int bid = blockIdx.x;
  const int g = bid & 7;
  const int w = bid >> 3;
  const int b0 = g * BROW;
  const int n0 = w * 32;
  const int wave = tid >> 6;
  const int lane = tid & 63;

  unsigned int* sgA = p.slots + (size_t)(g * 2 + 0) * 512;   // 32 slots x 64B
  unsigned int* sgB = p.slots + (size_t)(g * 2 + 1) * 512;
  unsigned int* arrA = sgA + (size_t)w * 16;
  unsigned int* arrB = sgB + (size_t)w * 16;

  unsigned short* y1bg = p.y1b + (size_t)g * BROW * NH;
  unsigned short* y2bg = p.y2b + (size_t)g * BROW * NH;
  float* pa_gg = p.pa + (size_t)g * BROW * NJ * 32;
  float* part1g = p.part1 + (size_t)g * BROW * 64;    // [32 rows][32 w][2]
  float* part2g = p.part2 + (size_t)g * BROW * 128;   // [32 rows][64 slot][2]

  // ---------------- P0: one-time setup ----------------
  if (tid < NJ) {
    alpha_l[tid] = 1.f / (1.f + expf(-p.alog[tid]));
    float lo = p.jlo[tid], hi = p.jhi[tid];
    jm_l[tid] = 0.5f * (hi + lo);
    jri_l[tid] = 2.f / (hi - lo);
    lo_l[tid] = lo; hi_l[tid] = hi;
    ddp_l[tid] = p.ddp[tid]; ba2_l[tid] = p.ba2[tid];
  }
  if (tid < NPD) { pm_l[tid] = p.pmean[tid]; psi_l[tid] = 1.f / p.pstd[tid]; bv_l[tid] = p.bv[tid]; }
  if (tid < 3) bo_l[tid] = p.bo[tid];
  if (tid < 16 * NJ) {
    pjA[tid] = p.ddp[tid % NJ]; pdqA[tid] = 0.f;
    pjB[tid] = p.ddp[tid % NJ]; pdqB[tid] = 0.f;
  }
  for (int idx = tid; idx < NH; idx += 256) {
    g1l[idx] = p.g1[idx]; be1l[idx] = p.be1[idx];
    g2l[idx] = p.g2[idx]; be2l[idx] = p.be2[idx];
  }
  for (int idx = tid; idx < BROW * NH; idx += 256) {
    int r = idx >> 10, k = idx & (NH - 1);
    w2l[r * W2S + k] = f2bf(p.W2[(size_t)(n0 + r) * NH + k]);
  }
  for (int idx = tid; idx < 16 * 32; idx += 256) {   // Wa2 slice -> LDS
    int rr = idx >> 5, cc = idx & 31;
    wa2l[rr * 40 + cc] = (rr < NJ) ? f2bf(p.Wa2[(size_t)rr * NH + n0 + cc]) : (unsigned short)0;
  }
  {  // zc = z @ W1z^T + b1 (constant across steps), all 32 rows
    int r = tid >> 3, cq = tid & 7;
    int nb = n0 + cq * 4;
    const float* zr = p.z + (size_t)(b0 + r) * 64;
    const float* w1r = p.W1 + (size_t)nb * NPIN + 75;
    float a0 = p.b1[nb], a1 = p.b1[nb + 1], a2 = p.b1[nb + 2], a3 = p.b1[nb + 3];
    for (int k = 0; k < 64; ++k) {
      float zv = zr[k];
      a0 += zv * w1r[k]; a1 += zv * w1r[NPIN + k];
      a2 += zv * w1r[2 * NPIN + k]; a3 += zv * w1r[3 * NPIN + k];
    }
    f32x4 st = {a0, a1, a2, a3};
    *(f32x4*)(p.zc + (size_t)(b0 + r) * NH + nb) = st;
  }
  for (int idx = tid; idx < 4 * NH; idx += 256) {  // Wa1 -> bf16 ws
    int r = idx >> 10, k = idx & (NH - 1);
    int row = n0 + g * 4 + r;
    p.wa1b[(size_t)row * NH + k] = f2bf(p.Wa1[(size_t)row * NH + k]);
  }
  if (bid == 1) {  // [Wo(3); Wv(42); zeros(3)] padded to 48 rows
    for (int idx = tid; idx < 48 * NH; idx += 256) {
      int r = idx >> 10, k = idx & (NH - 1);
      unsigned short v = 0;
      if (r < 3) v = f2bf(p.Wo[(size_t)r * NH + k]);
      else if (r < 45) v = f2bf(p.Wv[(size_t)(r - 3) * NH + k]);
      p.wexb[idx] = v;
    }
  }
  gbar(p.gcnt, 256u);

  // ---------------- phase lambdas (per half h: rows h*16 .. h*16+15) --------
  // Stage 16-row y tile (sc0) -> albuf, normalizing with producer partials.
  auto stage_ln = [&](int h, const unsigned short* yg, const float* part, bool wide,
                      const float* gl, const float* bl) {
    const int r = tid >> 4, cl = tid & 15;
    const int hofs = h * 16;
    const unsigned short* src = yg + (size_t)(hofs + r) * NH + cl * 8;
    unsigned short* dst = &albuf[r * AS + cl * 8];
    short8 v[8];
#pragma unroll
    for (int i = 0; i < 8; ++i) ld16_sc0(src + (size_t)i * 128, v[i]);
    f32x4 q0, q1 = {0, 0, 0, 0};
    if (wide) {
      const float* pp = part + (size_t)(hofs + r) * 128 + cl * 8;
      ldf4_sc0(pp, q0); ldf4_sc0(pp + 4, q1);
    } else {
      const float* pp = part + (size_t)(hofs + r) * 64 + cl * 4;
      ldf4_sc0(pp, q0);
    }
    vwait0();
    float s = q0[0] + q0[2] + q1[0] + q1[2];
    float q = q0[1] + q0[3] + q1[1] + q1[3];
#pragma unroll
    for (int off = 8; off; off >>= 1) {
      s += __shfl_down(s, off, 16);
      q += __shfl_down(q, off, 16);
    }
    s = __shfl(s, 0, 16); q = __shfl(q, 0, 16);
    float m = s * (1.f / 1024.f);
    float rs = rsqrtf(q * (1.f / 1024.f) - m * m + 1e-5f);
    float nmrs = -m * rs;
#pragma unroll
    for (int i = 0; i < 8; ++i) {
      int c = cl * 8 + i * 128;
      f32x4 ga = *(const f32x4*)(gl + c);
      f32x4 gb = *(const f32x4*)(gl + c + 4);
      f32x4 ba = *(const f32x4*)(bl + c);
      f32x4 bb = *(const f32x4*)(bl + c + 4);
      float xn[8];
#pragma unroll
      for (int jj = 0; jj < 8; ++jj) {
        float x = bf2f((unsigned short)v[i][jj]);
        float tn = fmaf(x, rs, nmrs);
        float gg = (jj < 4) ? ga[jj] : gb[jj - 4];
        float bv2 = (jj < 4) ? ba[jj] : bb[jj - 4];
        xn[jj] = fmaxf(fmaf(tn, gg, bv2), 0.f);
      }
      uint4 pk = {cvt_pk_bf16(xn[0], xn[1]), cvt_pk_bf16(xn[2], xn[3]),
                  cvt_pk_bf16(xn[4], xn[5]), cvt_pk_bf16(xn[6], xn[7])};
      *(uint4*)(dst + i * 128) = pk;
    }
  };

  // P1 per half: 16 rows x 16 threads x 2 cols.
  auto P1 = [&](int h, int t) {
    const int r = tid >> 4, cl = tid & 15;
    const int nb = n0 + cl * 2;
    const int grow = b0 + h * 16 + r;
    const float* pj = h ? pjB : pjA;
    const float* pdq = h ? pdqB : pdqA;
    const float* zrow = p.zc + (size_t)grow * NH;
    float a0 = zrow[nb], a1 = zrow[nb + 1];
    const float* w0 = p.W1 + (size_t)nb * NPIN;
    const float* w1p = w0 + NPIN;
    const float* ob = p.obs + ((size_t)grow * NS + t) * 51;
    for (int o = 0; o < 51; ++o) {
      float ov = ob[o];
      a0 += ov * w0[24 + o]; a1 += ov * w1p[24 + o];
    }
    float xj[24];
#pragma unroll
    for (int j = 0; j < NJ; ++j) {
      xj[j] = (pj[r * NJ + j] - jm_l[j]) * jri_l[j];
      xj[12 + j] = pdq[r * NJ + j];
    }
#pragma unroll
    for (int k = 0; k < 24; ++k) {
      a0 += xj[k] * w0[k]; a1 += xj[k] * w1p[k];
    }
    *(unsigned*)(y1bg + (size_t)(h * 16 + r) * NH + nb) = cvt_pk_bf16(a0, a1);
    float s = a0 + a1, q = a0 * a0 + a1 * a1;
#pragma unroll
    for (int off = 8; off; off >>= 1) {
      s += __shfl_down(s, off, 16);
      q += __shfl_down(q, off, 16);
    }
    if (cl == 0) {
      f32x2 pw = {s, q};
      *(f32x2*)(part1g + (size_t)(h * 16 + r) * 64 + w * 2) = pw;
    }
  };

  auto Yph = [&](int h) {  // h1 = relu(LN1(y1_h)); y2_h = h1 @ W2^T + b2 (+ part2)
    stage_ln(h, y1bg, part1g, false, g1l, be1l);
    __syncthreads();
    if (wave < 2) {
      const int ct = wave;
      const int kq = (lane >> 4) * 8;
      const unsigned short* a = &albuf[(lane & 15) * AS + kq];
      const unsigned short* b = &w2l[(ct * 16 + (lane & 15)) * W2S + kq];
      f32x4 acc = dot1024(a, b);
      int col = n0 + ct * 16 + (lane & 15);
      float b2v = p.b2[col];
      float sv[4], qv[4];
#pragma unroll
      for (int i = 0; i < 4; ++i) {
        int row = (lane >> 4) * 4 + i;
        float val = acc[i] + b2v;
        y2bg[(size_t)(h * 16 + row) * NH + col] = f2bf(val);
        sv[i] = val; qv[i] = val * val;
      }
#pragma unroll
      for (int mask = 1; mask < 16; mask <<= 1) {
#pragma unroll
        for (int i = 0; i < 4; ++i) {
          sv[i] += __shfl_xor(sv[i], mask, 64);
          qv[i] += __shfl_xor(qv[i], mask, 64);
        }
      }
      if ((lane & 15) == 0) {
        int rbase = (lane >> 4) * 4;
#pragma unroll
        for (int i = 0; i < 4; ++i) {
          f32x2 pw = {sv[i], qv[i]};
          *(f32x2*)(part2g + (size_t)(h * 16 + rbase + i) * 128 + (w * 2 + ct) * 2) = pw;
        }
      }
    }
  };

  auto Zph = [&](int h, int t) {  // h=relu(LN2(y2_h)); t1; pa partial; heads
    stage_ln(h, y2bg, part2g, true, g2l, be2l);
    __syncthreads();
    if (wave < 2) {
      const int ct = wave;
      const int kq = (lane >> 4) * 8;
      const unsigned short* a = &albuf[(lane & 15) * AS + kq];
      const unsigned short* b = p.wa1b + (size_t)(n0 + ct * 16 + (lane & 15)) * NH + kq;
      f32x4 acc = dot1024(a, b);
      int lcol = ct * 16 + (lane & 15);
      float bav = p.ba1[n0 + lcol];
#pragma unroll
      for (int i = 0; i < 4; ++i) {
        int row = (lane >> 4) * 4 + i;
        t1l[row * 40 + lcol] = f2bf(fmaxf(acc[i] + bav, 0.f));
      }
    }
    __syncthreads();
    if (wave == 0) {  // pa[16 rows][12 j] partial over this WG's 32 cols
      int k0 = (lane >> 4) * 8;
      short8 a8 = *(const short8*)&t1l[(lane & 15) * 40 + k0];
      short8 b8 = *(const short8*)&wa2l[(lane & 15) * 40 + k0];
      f32x4 z4 = {0.f, 0.f, 0.f, 0.f};
      f32x4 d = __builtin_amdgcn_mfma_f32_16x16x32_bf16(a8, b8, z4, 0, 0, 0);
      int j = lane & 15;
      if (j < NJ) {
#pragma unroll
        for (int i = 0; i < 4; ++i) {
          int row = (lane >> 4) * 4 + i;
          pa_gg[((size_t)(h * 16 + row) * NJ + j) * 32 + w] = d[i];
        }
      }
    }
    if (wave == 3 && w >= 26 + 3 * h && w < 29 + 3 * h) {  // heads: 3 tiles/half
      const int cte = w - (26 + 3 * h);
      const int kq = (lane >> 4) * 8;
      const unsigned short* a = &albuf[(lane & 15) * AS + kq];
      const unsigned short* b = p.wexb + (size_t)(cte * 16 + (lane & 15)) * NH + kq;
      f32x4 acc = dot1024(a, b);
      int ec = cte * 16 + (lane & 15);
#pragma unroll
      for (int i = 0; i < 4; ++i) {
        int row = (lane >> 4) * 4 + i;
        int bb = b0 + h * 16 + row;
        if (ec < 3) {
          float val = acc[i] + bo_l[ec];
          p.out_gmu[((size_t)bb * NS + t) * NPD + 39 + ec] = (val - pm_l[39 + ec]) * psi_l[39 + ec];
        } else if (ec < 45) {
          int sv2 = ec - 3;
          float val = acc[i] + bv_l[sv2];
          float sig = 0.05f + 0.45f / (1.f + expf(-val));
          p.out_ls[((size_t)bb * NS + t) * NPD + sv2] = logf(sig);
        }
      }
    }
  };

  auto Xph = [&](int h, int tp) {  // reduce pa -> a; state update; outputs
    float* pj = h ? pjB : pjA;
    float* pdq = h ? pdqB : pdqA;
    if (tid < 16 * NJ) {
      const int e = tid;
      const float* pp = pa_gg + ((size_t)h * 16 * NJ + e) * 32;
      f32x4 u[8];
#pragma unroll
      for (int c2 = 0; c2 < 8; ++c2) ldf4_sc0(pp + c2 * 4, u[c2]);
      vwait0();
      f32x4 ss = ((u[0] + u[1]) + (u[2] + u[3])) + ((u[4] + u[5]) + (u[6] + u[7]));
      float sum = ss[0] + ss[1] + ss[2] + ss[3];
      int r = e / NJ, j = e - r * NJ;
      float av = tanhf(sum + ba2_l[j]);
      float old = pj[e];
      float tgt = av * 0.25f + ddp_l[j];
      float cj = old + alpha_l[j] * (tgt - old);
      cj = fminf(fmaxf(cj, lo_l[j]), hi_l[j]);
      pdq[e] = (cj - old) * 30.f;
      pj[e] = cj;
      if (w == 0) {
        size_t o = ((size_t)(b0 + h * 16 + r) * NS + tp) * NJ + j;
        p.out_joint[o] = cj;
        p.out_act[o] = av;
      }
    }
    __syncthreads();
    if (w == 0) {  // agent FK + normalize -> graph_x_mu[:, :, 0:39]
      for (int idx = tid; idx < 16 * 39; idx += 256) {
        int r = idx / 39, m = idx - r * 39;
        float s = p.fkb[m];
        const float* fw = p.fkW + m * NJ;
#pragma unroll
        for (int j = 0; j < NJ; ++j) s += pj[r * NJ + j] * fw[j];
        p.out_gmu[((size_t)(b0 + h * 16 + r) * NS + tp) * NPD + m] = (s - pm_l[m]) * psi_l[m];
      }
    }
  };

  // ---------------- interleaved step loop: halves A/B phase-shifted --------
  unsigned nbA = 0, nbB = 0;
  // prologue: t = 0
  P1(0, 0); arrive_bar(arrA, tid); ++nbA;
  P1(1, 0); arrive_bar(arrB, tid); ++nbB;
  for (int t = 0; t < NS; ++t) {
    wait_bar(sgA, nbA, wave, lane);        // y1_A + part1_A ready
    Yph(0);  arrive_bar(arrA, tid); ++nbA;
    wait_bar(sgB, nbB, wave, lane);        // y1_B ready (settled under Yph A)
    Yph(1);  arrive_bar(arrB, tid); ++nbB;
    wait_bar(sgA, nbA, wave, lane);        // y2_A + part2_A ready
    Zph(0, t); arrive_bar(arrA, tid); ++nbA;
    wait_bar(sgB, nbB, wave, lane);
    Zph(1, t); arrive_bar(arrB, tid); ++nbB;
    wait_bar(sgA, nbA, wave, lane);        // pa_A + heads_A ready
    Xph(0, t);
    if (t + 1 < NS) { P1(0, t + 1); arrive_bar(arrA, tid); ++nbA; }
    wait_bar(sgB, nbB, wave, lane);
    Xph(1, t);
    if (t + 1 < NS) { P1(1, t + 1); arrive_bar(arrB, tid); ++nbB; }
  }
}

extern "C" void kernel_launch(void* const* d_in, const int* in_sizes, int n_in,
                              void* d_out, int out_size, void* d_ws, size_t ws_size,
                              hipStream_t stream) {
  (void)in_sizes; (void)n_in; (void)out_size; (void)ws_size;
  char* ws = (char*)d_ws;
  Params p;
  p.z = (const float*)d_in[0];   p.obs = (const float*)d_in[1];
  p.W1 = (const float*)d_in[2];  p.b1 = (const float*)d_in[3];
  p.g1 = (const float*)d_in[4];  p.be1 = (const float*)d_in[5];
  p.W2 = (const float*)d_in[6];  p.b2 = (const float*)d_in[7];
  p.g2 = (const float*)d_in[8];  p.be2 = (const float*)d_in[9];
  p.Wa1 = (const float*)d_in[10]; p.ba1 = (const float*)d_in[11];
  p.Wa2 = (const float*)d_in[12]; p.ba2 = (const float*)d_in[13];
  p.Wo = (const float*)d_in[14]; p.bo = (const float*)d_in[15];
  p.Wv = (const float*)d_in[16]; p.bv = (const float*)d_in[17];
  p.alog = (const float*)d_in[18];
  p.fkW = (const float*)d_in[19]; p.fkb = (const float*)d_in[20];
  p.pmean = (const float*)d_in[21]; p.pstd = (const float*)d_in[22];
  p.jlo = (const float*)d_in[23]; p.jhi = (const float*)d_in[24];
  p.ddp = (const float*)d_in[25];

  float* out = (float*)d_out;
  p.out_gmu = out;                                 // [256,128,42]
  p.out_joint = out + (size_t)256 * 128 * 42;      // [256,128,12]
  p.out_act = p.out_joint + (size_t)256 * 128 * 12;
  p.out_ls = p.out_act + (size_t)256 * 128 * 12;   // [256,128,42]

  p.gcnt = (unsigned int*)(ws + 0);
  p.slots = (unsigned int*)(ws + 1024);            // 16 regions x 32 slots x 64B = 32KB
  size_t off = (size_t)1 << 16;
  p.zc = (float*)(ws + off);                 off += (size_t)NB * NH * 4;          // 1MB
  p.y1b = (unsigned short*)(ws + off);       off += (size_t)NB * NH * 2;          // 512KB
  p.y2b = (unsigned short*)(ws + off);       off += (size_t)NB * NH * 2;          // 512KB
  p.pa = (float*)(ws + off);                 off += (size_t)8 * 32 * 12 * 32 * 4; // 384KB
  p.part1 = (float*)(ws + off);              off += (size_t)8 * 32 * 64 * 4;      // 64KB
  p.part2 = (float*)(ws + off);              off += (size_t)8 * 32 * 128 * 4;     // 128KB
  p.wa1b = (unsigned short*)(ws + off);      off += (size_t)NH * NH * 2;          // 2MB
  p.wexb = (unsigned short*)(ws + off);

  // counters/slots must start at 0 each call (monotonic within a call)
  hipMemsetAsync(d_ws, 0, 1 << 16, stream);
  decoder_persistent<<<dim3(256), dim3(256), 0, stream>>>(p);
}

// Round 12
// 3668.839 us; speedup vs baseline: 1.2823x; 1.2823x over previous
//
#include <hip/hip_runtime.h>
#include <math.h>

// Decoder_82231443849250: persistent-kernel recurrent MLP decoder. Round 12.
// = Round-10 EXACTLY (best validated: 3673us) with ONE change:
//   barrier slots spaced 4KB apart (was 64B). Theory: Infinity-Cache channels
//   interleave at >=2KB granularity, so 64B-spaced slots all mapped to ONE
//   LLC channel -> 32 arrival RMWs serialized (~6us/barrier, constant across
//   r5/r7/r10 protocol variants). 4KB spacing puts each WG's slot on its own
//   channel: parallel arrivals, parallel per-lane poll.
// All spins carry an s_memrealtime bailout so bugs terminate instead of hang.

#define NB 256
#define NS 128
#define NH 1024
#define NJ 12
#define NPIN 139
#define NPD 42
#define WPG 32
#define BROW 32
#define W2S 1032
#define AS 1032
#define SLOTSTRIDE 1024  // dwords = 4KB between slots (one per LLC channel granule)

typedef __attribute__((ext_vector_type(8))) short short8;
typedef __attribute__((ext_vector_type(4))) float f32x4;
typedef __attribute__((ext_vector_type(4))) unsigned short u16x4;

struct Params {
  const float* z; const float* obs; const float* W1; const float* b1;
  const float* g1; const float* be1; const float* W2; const float* b2;
  const float* g2; const float* be2; const float* Wa1; const float* ba1;
  const float* Wa2; const float* ba2; const float* Wo; const float* bo;
  const float* Wv; const float* bv; const float* alog; const float* fkW;
  const float* fkb; const float* pmean; const float* pstd; const float* jlo;
  const float* jhi; const float* ddp;
  float* out_gmu; float* out_joint; float* out_act; float* out_ls;
  float* zc; float* pa; float* part1; float* part2;
  unsigned short* y1b; unsigned short* y2b;
  unsigned short* wa1b; unsigned short* wexb;
  unsigned int* gcnt; unsigned int* slots;
};

__device__ __forceinline__ unsigned short f2bf(float x) {
  union { float f; unsigned u; } v; v.f = x;
  unsigned r = v.u + 0x7FFFu + ((v.u >> 16) & 1u);
  return (unsigned short)(r >> 16);
}
__device__ __forceinline__ float bf2f(unsigned short x) {
  union { unsigned u; float f; } v; v.u = ((unsigned)x) << 16;
  return v.f;
}
__device__ __forceinline__ unsigned cvt_pk_bf16(float lo, float hi) {
  unsigned r;
  asm("v_cvt_pk_bf16_f32 %0, %1, %2" : "=v"(r) : "v"(lo), "v"(hi));
  return r;
}
// sc0 loads: fresh-by-L1-eviction data reads (each phase streams >=128KB
// through the 32KB L1), hit the shared XCD L2.
__device__ __forceinline__ void ld16_sc0(const unsigned short* p, short8& d) {
  asm volatile("global_load_dwordx4 %0, %1, off sc0" : "=v"(d) : "v"(p));
}
__device__ __forceinline__ void ldf4_sc0(const float* p, f32x4& d) {
  asm volatile("global_load_dwordx4 %0, %1, off sc0" : "=v"(d) : "v"(p));
}
__device__ __forceinline__ void vwait0() {
  asm volatile("s_waitcnt vmcnt(0)" ::: "memory");
  __builtin_amdgcn_sched_barrier(0);  // rule #18: pin uses after the wait
}

__device__ __forceinline__ f32x4 dot1024(const unsigned short* a, const unsigned short* b) {
  const short8* ap = (const short8*)a;
  const short8* bp = (const short8*)b;
  f32x4 acc0 = {0.f, 0.f, 0.f, 0.f};
  f32x4 acc1 = {0.f, 0.f, 0.f, 0.f};
#pragma unroll 4
  for (int k8 = 0; k8 < 128; k8 += 8) {
    acc0 = __builtin_amdgcn_mfma_f32_16x16x32_bf16(ap[k8], bp[k8], acc0, 0, 0, 0);
    acc1 = __builtin_amdgcn_mfma_f32_16x16x32_bf16(ap[k8 + 4], bp[k8 + 4], acc1, 0, 0, 0);
  }
  return acc0 + acc1;
}

// ---- one-time global barrier (cross-XCD safe): full fences, used once.
__device__ __forceinline__ void gbar(unsigned int* c, unsigned int target) {
  __threadfence();
  __syncthreads();
  if (threadIdx.x == 0) {
    __hip_atomic_fetch_add(c, 1u, __ATOMIC_RELEASE, __HIP_MEMORY_SCOPE_AGENT);
    unsigned long long t0 = __builtin_amdgcn_s_memrealtime();
    while (__hip_atomic_load(c, __ATOMIC_ACQUIRE, __HIP_MEMORY_SCOPE_AGENT) < target) {
      __builtin_amdgcn_s_sleep(16);
      if (__builtin_amdgcn_s_memrealtime() - t0 > (1ull << 25)) break;
    }
  }
  __syncthreads();
  __threadfence();
}

// ---- slot-wait: wave 0 polls all 32 slots (sc0 sc1 -> coherence point),
// slots 4KB apart -> 32 different LLC channels, parallel RTTs.
__device__ __forceinline__ void slot_wait(const unsigned int* sg, unsigned target, int lane) {
  const unsigned int* myslot = sg + (size_t)(lane & 31) * SLOTSTRIDE;
  unsigned long long t0 = __builtin_amdgcn_s_memrealtime();
  for (;;) {
    unsigned v;
    asm volatile("global_load_dword %0, %1, off sc0 sc1\n\t"
                 "s_waitcnt vmcnt(0)"
                 : "=v"(v) : "v"(myslot) : "memory");
    if (__all(v >= target)) break;
    __builtin_amdgcn_s_sleep(1);
    if (__builtin_amdgcn_s_memrealtime() - t0 > (1ull << 23)) break;  // bail, never hang
  }
}

// ---- full slot barrier: atomic arrival (own 4KB-spaced slot) + poll.
__device__ __forceinline__ void xbar2(unsigned int* sg, int w, unsigned target,
                                      int wave, int lane) {
  asm volatile("s_waitcnt vmcnt(0)" ::: "memory");
  __syncthreads();
  if (wave == 0) {
    if (lane == 0)
      __hip_atomic_fetch_add(sg + (size_t)w * SLOTSTRIDE, 1u, __ATOMIC_RELAXED,
                             __HIP_MEMORY_SCOPE_AGENT);
    slot_wait(sg, target, lane);
  }
  __syncthreads();
}

__global__ __launch_bounds__(256, 1) void decoder_persistent(Params p) {
  __shared__ unsigned short w2l[BROW * W2S];    // 66 KB: W2 col-slice bf16
  __shared__ unsigned short albuf[BROW * AS];   // 66 KB: normalized A tile bf16
  __shared__ float g1l[NH], be1l[NH], g2l[NH], be2l[NH];  // 16 KB
  __shared__ unsigned short t1l[BROW * 40];     // 2.5 KB
  __shared__ unsigned short wa2l[16 * 40];      // 1.25 KB
  __shared__ float pj_l[BROW * NJ], pdq_l[BROW * NJ];
  __shared__ float alpha_l[NJ], jm_l[NJ], jri_l[NJ], lo_l[NJ], hi_l[NJ], ddp_l[NJ], ba2_l[NJ];
  __shared__ float pm_l[NPD], psi_l[NPD], bv_l[NPD], bo_l[4];

  const int tid = threadIdx.x;
  const int bid = blockIdx.x;
  const int g = bid & 7;
  const int w = bid >> 3;
  const int b0 = g * BROW;
  const int n0 = w * 32;
  const int wave = tid >> 6;
  const int lane = tid & 63;

  unsigned int* sg = p.slots + (size_t)g * WPG * SLOTSTRIDE;  // 32 x 4KB slots
  unsigned short* y1bg = p.y1b + (size_t)g * BROW * NH;
  unsigned short* y2bg = p.y2b + (size_t)g * BROW * NH;
  float* pa_gg = p.pa + (size_t)g * BROW * NJ * 32;
  float* part1g = p.part1 + (size_t)g * BROW * 64;    // [32 rows][32 w][2]
  float* part2g = p.part2 + (size_t)g * BROW * 128;   // [32 rows][32 w][2 ct][2]

  // ---------------- P0: one-time setup ----------------
  if (tid < NJ) {
    alpha_l[tid] = 1.f / (1.f + expf(-p.alog[tid]));
    float lo = p.jlo[tid], hi = p.jhi[tid];
    jm_l[tid] = 0.5f * (hi + lo);
    jri_l[tid] = 2.f / (hi - lo);
    lo_l[tid] = lo; hi_l[tid] = hi;
    ddp_l[tid] = p.ddp[tid]; ba2_l[tid] = p.ba2[tid];
  }
  if (tid < NPD) { pm_l[tid] = p.pmean[tid]; psi_l[tid] = 1.f / p.pstd[tid]; bv_l[tid] = p.bv[tid]; }
  if (tid < 3) bo_l[tid] = p.bo[tid];
  for (int idx = tid; idx < BROW * NJ; idx += 256) { pj_l[idx] = p.ddp[idx % NJ]; pdq_l[idx] = 0.f; }
  for (int idx = tid; idx < NH; idx += 256) {
    g1l[idx] = p.g1[idx]; be1l[idx] = p.be1[idx];
    g2l[idx] = p.g2[idx]; be2l[idx] = p.be2[idx];
  }
  for (int idx = tid; idx < BROW * NH; idx += 256) {
    int r = idx >> 10, k = idx & (NH - 1);
    w2l[r * W2S + k] = f2bf(p.W2[(size_t)(n0 + r) * NH + k]);
  }
  for (int idx = tid; idx < 16 * 32; idx += 256) {   // Wa2 slice -> LDS
    int rr = idx >> 5, cc = idx & 31;
    wa2l[rr * 40 + cc] = (rr < NJ) ? f2bf(p.Wa2[(size_t)rr * NH + n0 + cc]) : (unsigned short)0;
  }
  {  // zc = z @ W1z^T + b1 (constant across steps)
    int r = tid >> 3, cq = tid & 7;
    int nb = n0 + cq * 4;
    const float* zr = p.z + (size_t)(b0 + r) * 64;
    const float* w1r = p.W1 + (size_t)nb * NPIN + 75;
    float a0 = p.b1[nb], a1 = p.b1[nb + 1], a2 = p.b1[nb + 2], a3 = p.b1[nb + 3];
    for (int k = 0; k < 64; ++k) {
      float zv = zr[k];
      a0 += zv * w1r[k]; a1 += zv * w1r[NPIN + k];
      a2 += zv * w1r[2 * NPIN + k]; a3 += zv * w1r[3 * NPIN + k];
    }
    f32x4 st = {a0, a1, a2, a3};
    *(f32x4*)(p.zc + (size_t)(b0 + r) * NH + nb) = st;
  }
  for (int idx = tid; idx < 4 * NH; idx += 256) {  // Wa1 -> bf16 ws
    int r = idx >> 10, k = idx & (NH - 1);
    int row = n0 + g * 4 + r;
    p.wa1b[(size_t)row * NH + k] = f2bf(p.Wa1[(size_t)row * NH + k]);
  }
  if (bid == 1) {  // [Wo(3); Wv(42); zeros(3)] padded to 48 rows
    for (int idx = tid; idx < 48 * NH; idx += 256) {
      int r = idx >> 10, k = idx & (NH - 1);
      unsigned short v = 0;
      if (r < 3) v = f2bf(p.Wo[(size_t)r * NH + k]);
      else if (r < 45) v = f2bf(p.Wv[(size_t)(r - 3) * NH + k]);
      p.wexb[idx] = v;
    }
  }
  gbar(p.gcnt, 256u);

  // ---------------- phase lambdas ----------------
  auto stage_ln_apply = [&](const unsigned short* yg, const float* part, bool wide,
                            const float* gl, const float* bl) {
    const int r = tid >> 3, cq = tid & 7;
    const unsigned short* src = yg + (size_t)r * NH + cq * 8;
    unsigned short* dst = &albuf[r * AS + cq * 8];
    short8 v[16];
#pragma unroll
    for (int i = 0; i < 16; ++i) ld16_sc0(src + (size_t)i * 64, v[i]);
    const int fpr = wide ? 128 : 64;
    const float* pp = part + (size_t)r * fpr + cq * (fpr >> 3);
    f32x4 p0, p1, p2 = {0, 0, 0, 0}, p3 = {0, 0, 0, 0};
    ldf4_sc0(pp, p0);
    ldf4_sc0(pp + 4, p1);
    if (wide) { ldf4_sc0(pp + 8, p2); ldf4_sc0(pp + 12, p3); }
    vwait0();
    float s = p0[0] + p0[2] + p1[0] + p1[2];
    float q = p0[1] + p0[3] + p1[1] + p1[3];
    if (wide) {
      s += p2[0] + p2[2] + p3[0] + p3[2];
      q += p2[1] + p2[3] + p3[1] + p3[3];
    }
#pragma unroll
    for (int off = 4; off; off >>= 1) {
      s += __shfl_down(s, off, 8);
      q += __shfl_down(q, off, 8);
    }
    s = __shfl(s, 0, 8); q = __shfl(q, 0, 8);
    float m = s * (1.f / 1024.f);
    float rs = rsqrtf(q * (1.f / 1024.f) - m * m + 1e-5f);
    float nmrs = -m * rs;
#pragma unroll
    for (int i = 0; i < 16; ++i) {
      int c = cq * 8 + i * 64;
      f32x4 ga = *(const f32x4*)(gl + c);
      f32x4 gb = *(const f32x4*)(gl + c + 4);
      f32x4 ba = *(const f32x4*)(bl + c);
      f32x4 bb = *(const f32x4*)(bl + c + 4);
      float xn[8];
#pragma unroll
      for (int jj = 0; jj < 8; ++jj) {
        float x = bf2f((unsigned short)v[i][jj]);
        float tn = fmaf(x, rs, nmrs);
        float gg = (jj < 4) ? ga[jj] : gb[jj - 4];
        float bv2 = (jj < 4) ? ba[jj] : bb[jj - 4];
        xn[jj] = fmaxf(fmaf(tn, gg, bv2), 0.f);
      }
      uint4 pk = {cvt_pk_bf16(xn[0], xn[1]), cvt_pk_bf16(xn[2], xn[3]),
                  cvt_pk_bf16(xn[4], xn[5]), cvt_pk_bf16(xn[6], xn[7])};
      *(uint4*)(dst + i * 64) = pk;
    }
  };

  // P1 split: obs-part (state-independent) / finish (state-dependent).
  auto P1_obs = [&](int t) -> f32x4 {
    int r = tid >> 3, cq = tid & 7;
    int nb = n0 + cq * 4;
    f32x4 acc = *(const f32x4*)(p.zc + (size_t)(b0 + r) * NH + nb);
    const float* w1r = p.W1 + (size_t)nb * NPIN;
    const float* ob = p.obs + ((size_t)(b0 + r) * NS + t) * 51;
    for (int o = 0; o < 51; ++o) {
      float ov = ob[o];
      acc[0] += ov * w1r[24 + o]; acc[1] += ov * w1r[NPIN + 24 + o];
      acc[2] += ov * w1r[2 * NPIN + 24 + o]; acc[3] += ov * w1r[3 * NPIN + 24 + o];
    }
    return acc;
  };
  auto P1_fin = [&](f32x4 acc) {
    int r = tid >> 3, cq = tid & 7;
    int nb = n0 + cq * 4;
    float xj[24];
#pragma unroll
    for (int j = 0; j < NJ; ++j) {
      xj[j] = (pj_l[r * NJ + j] - jm_l[j]) * jri_l[j];
      xj[12 + j] = pdq_l[r * NJ + j];
    }
    const float* w1r = p.W1 + (size_t)nb * NPIN;
#pragma unroll
    for (int k = 0; k < 24; ++k) {
      float xv = xj[k];
      acc[0] += xv * w1r[k]; acc[1] += xv * w1r[NPIN + k];
      acc[2] += xv * w1r[2 * NPIN + k]; acc[3] += xv * w1r[3 * NPIN + k];
    }
    u16x4 hv = {f2bf(acc[0]), f2bf(acc[1]), f2bf(acc[2]), f2bf(acc[3])};
    *(u16x4*)(y1bg + (size_t)r * NH + nb) = hv;
    float s = acc[0] + acc[1] + acc[2] + acc[3];
    float q = acc[0] * acc[0] + acc[1] * acc[1] + acc[2] * acc[2] + acc[3] * acc[3];
#pragma unroll
    for (int off = 4; off; off >>= 1) {
      s += __shfl_down(s, off, 8);
      q += __shfl_down(q, off, 8);
    }
    if ((tid & 7) == 0) {
      float* pw = part1g + (size_t)r * 64 + w * 2;
      pw[0] = s; pw[1] = q;
    }
  };

  auto Yphase = [&]() {  // h1 = relu(LN1(y1)); y2 = h1 @ W2^T + b2 + LN2 partials
    stage_ln_apply(y1bg, part1g, false, g1l, be1l);
    __syncthreads();
    int rt = wave >> 1, ct = wave & 1;
    int kq = (lane >> 4) * 8;
    const unsigned short* a = &albuf[(rt * 16 + (lane & 15)) * AS + kq];
    const unsigned short* b = &w2l[(ct * 16 + (lane & 15)) * W2S + kq];
    f32x4 acc = dot1024(a, b);
    int col = n0 + ct * 16 + (lane & 15);
    float b2v = p.b2[col];
    float sv[4], qv[4];
#pragma unroll
    for (int i = 0; i < 4; ++i) {
      int row = rt * 16 + (lane >> 4) * 4 + i;
      float val = acc[i] + b2v;
      y2bg[(size_t)row * NH + col] = f2bf(val);
      sv[i] = val; qv[i] = val * val;
    }
#pragma unroll
    for (int mask = 1; mask < 16; mask <<= 1) {
#pragma unroll
      for (int i = 0; i < 4; ++i) {
        sv[i] += __shfl_xor(sv[i], mask, 64);
        qv[i] += __shfl_xor(qv[i], mask, 64);
      }
    }
    if ((lane & 15) == 0) {
      int rbase = rt * 16 + (lane >> 4) * 4;
#pragma unroll
      for (int i = 0; i < 4; ++i) {
        float* pw = part2g + (size_t)(rbase + i) * 128 + (w * 2 + ct) * 2;
        pw[0] = sv[i]; pw[1] = qv[i];
      }
    }
  };

  auto Zphase = [&](int t) {  // h = relu(LN2(y2)); t1 -> LDS; pa partials; heads
    stage_ln_apply(y2bg, part2g, true, g2l, be2l);
    __syncthreads();
    int rt = wave >> 1, ct = wave & 1;
    int kq = (lane >> 4) * 8;
    {
      const unsigned short* a = &albuf[(rt * 16 + (lane & 15)) * AS + kq];
      const unsigned short* b = p.wa1b + (size_t)(n0 + ct * 16 + (lane & 15)) * NH + kq;
      f32x4 acc = dot1024(a, b);
      int lcol = ct * 16 + (lane & 15);
      float bav = p.ba1[n0 + lcol];
#pragma unroll
      for (int i = 0; i < 4; ++i) {
        int row = rt * 16 + (lane >> 4) * 4 + i;
        t1l[row * 40 + lcol] = f2bf(fmaxf(acc[i] + bav, 0.f));
      }
    }
    __syncthreads();
    if (wave < 2) {  // pa[32 rows][12 j] partial over this WG's 32 cols
      int k0 = (lane >> 4) * 8;
      short8 a8 = *(const short8*)&t1l[(wave * 16 + (lane & 15)) * 40 + k0];
      short8 b8 = *(const short8*)&wa2l[(lane & 15) * 40 + k0];
      f32x4 z4 = {0.f, 0.f, 0.f, 0.f};
      f32x4 d = __builtin_amdgcn_mfma_f32_16x16x32_bf16(a8, b8, z4, 0, 0, 0);
      int j = lane & 15;
      if (j < NJ) {
#pragma unroll
        for (int i = 0; i < 4; ++i) {
          int row = wave * 16 + (lane >> 4) * 4 + i;
          pa_gg[((size_t)row * NJ + j) * 32 + w] = d[i];
        }
      }
    }
    if (w >= 26 && wave == 3) {  // heads: [Wo|Wv] 6 extra 16x16 tiles off albuf
      int e = w - 26, cte = e >> 1, rte = e & 1;
      const unsigned short* a = &albuf[(rte * 16 + (lane & 15)) * AS + kq];
      const unsigned short* b = p.wexb + (size_t)(cte * 16 + (lane & 15)) * NH + kq;
      f32x4 acc = dot1024(a, b);
      int ec = cte * 16 + (lane & 15);
#pragma unroll
      for (int i = 0; i < 4; ++i) {
        int row = rte * 16 + (lane >> 4) * 4 + i;
        int bb = b0 + row;
        if (ec < 3) {
          float val = acc[i] + bo_l[ec];
          p.out_gmu[((size_t)bb * NS + t) * NPD + 39 + ec] = (val - pm_l[39 + ec]) * psi_l[39 + ec];
        } else if (ec < 45) {
          int sv2 = ec - 3;
          float val = acc[i] + bv_l[sv2];
          float sig = 0.05f + 0.45f / (1.f + expf(-val));
          p.out_ls[((size_t)bb * NS + t) * NPD + sv2] = logf(sig);
        }
      }
    }
  };

  auto Xmid = [&](int tp) {  // reduce pa -> a; state update; outputs for step tp
    for (int e = tid; e < BROW * NJ; e += 256) {
      const float* pp = pa_gg + (size_t)e * 32;
      f32x4 u[8];
#pragma unroll
      for (int c2 = 0; c2 < 8; ++c2) ldf4_sc0(pp + c2 * 4, u[c2]);
      vwait0();
      f32x4 ss = ((u[0] + u[1]) + (u[2] + u[3])) + ((u[4] + u[5]) + (u[6] + u[7]));
      float sum = ss[0] + ss[1] + ss[2] + ss[3];
      int r = e / NJ, j = e - r * NJ;
      float av = tanhf(sum + ba2_l[j]);
      float pj = pj_l[e];
      float tgt = av * 0.25f + ddp_l[j];
      float cj = pj + alpha_l[j] * (tgt - pj);
      cj = fminf(fmaxf(cj, lo_l[j]), hi_l[j]);
      pdq_l[e] = (cj - pj) * 30.f;
      pj_l[e] = cj;
      if (w == 0) {
        size_t o = ((size_t)(b0 + r) * NS + tp) * NJ + j;
        p.out_joint[o] = cj;
        p.out_act[o] = av;
      }
    }
    __syncthreads();
    if (w == 0) {  // agent FK + normalize -> graph_x_mu[:, :, 0:39]
      for (int idx = tid; idx < BROW * 39; idx += 256) {
        int r = idx / 39, m = idx - r * 39;
        float s = p.fkb[m];
        const float* fw = p.fkW + m * NJ;
#pragma unroll
        for (int j = 0; j < NJ; ++j) s += pj_l[r * NJ + j] * fw[j];
        p.out_gmu[((size_t)(b0 + r) * NS + tp) * NPD + m] = (s - pm_l[m]) * psi_l[m];
      }
    }
  };

  // ---------------- step loop ----------------
  unsigned nbar = 0;
  {  // prologue: t = 0
    f32x4 acc = P1_obs(0);
    P1_fin(acc);
    xbar2(sg, w, ++nbar, wave, lane);   // A: y1(0) + part1 complete
  }
  for (int t = 0; t < NS; ++t) {
    Yphase();
    xbar2(sg, w, ++nbar, wave, lane);   // B: y2 + part2 complete
    Zphase(t);
    // ---- split-phase barrier C: arrive, overlap obs-dot, wait ----
    unsigned tc = ++nbar;
    asm volatile("s_waitcnt vmcnt(0)" ::: "memory");
    __syncthreads();
    if (tid == 0)
      __hip_atomic_fetch_add(sg + (size_t)w * SLOTSTRIDE, 1u, __ATOMIC_RELAXED,
                             __HIP_MEMORY_SCOPE_AGENT);
    f32x4 acc = {0.f, 0.f, 0.f, 0.f};
    if (t + 1 < NS) acc = P1_obs(t + 1);   // state-independent, overlaps C settle
    if (wave == 0) slot_wait(sg, tc, lane);
    __syncthreads();                       // C: pa + heads complete
    Xmid(t);                               // state update
    if (t + 1 < NS) {
      P1_fin(acc);                         // uses fresh pj/pdq
      xbar2(sg, w, ++nbar, wave, lane);    // A: y1(t+1) + part1 complete
    }
  }
}

extern "C" void kernel_launch(void* const* d_in, const int* in_sizes, int n_in,
                              void* d_out, int out_size, void* d_ws, size_t ws_size,
                              hipStream_t stream) {
  (void)in_sizes; (void)n_in; (void)out_size; (void)ws_size;
  char* ws = (char*)d_ws;
  Params p;
  p.z = (const float*)d_in[0];   p.obs = (const float*)d_in[1];
  p.W1 = (const float*)d_in[2];  p.b1 = (const float*)d_in[3];
  p.g1 = (const float*)d_in[4];  p.be1 = (const float*)d_in[5];
  p.W2 = (const float*)d_in[6];  p.b2 = (const float*)d_in[7];
  p.g2 = (const float*)d_in[8];  p.be2 = (const float*)d_in[9];
  p.Wa1 = (const float*)d_in[10]; p.ba1 = (const float*)d_in[11];
  p.Wa2 = (const float*)d_in[12]; p.ba2 = (const float*)d_in[13];
  p.Wo = (const float*)d_in[14]; p.bo = (const float*)d_in[15];
  p.Wv = (const float*)d_in[16]; p.bv = (const float*)d_in[17];
  p.alog = (const float*)d_in[18];
  p.fkW = (const float*)d_in[19]; p.fkb = (const float*)d_in[20];
  p.pmean = (const float*)d_in[21]; p.pstd = (const float*)d_in[22];
  p.jlo = (const float*)d_in[23]; p.jhi = (const float*)d_in[24];
  p.ddp = (const float*)d_in[25];

  float* out = (float*)d_out;
  p.out_gmu = out;                                 // [256,128,42]
  p.out_joint = out + (size_t)256 * 128 * 42;      // [256,128,12]
  p.out_act = p.out_joint + (size_t)256 * 128 * 12;
  p.out_ls = p.out_act + (size_t)256 * 128 * 12;   // [256,128,42]

  p.gcnt = (unsigned int*)(ws + 0);
  p.slots = (unsigned int*)(ws + 4096);   // 8 groups x 32 slots x 4KB = 1MB
  size_t off = 4096 + (size_t)8 * WPG * SLOTSTRIDE * 4;  // = 4096 + 1MB
  p.zc = (float*)(ws + off);                 off += (size_t)NB * NH * 4;          // 1MB
  p.y1b = (unsigned short*)(ws + off);       off += (size_t)NB * NH * 2;          // 512KB
  p.y2b = (unsigned short*)(ws + off);       off += (size_t)NB * NH * 2;          // 512KB
  p.pa = (float*)(ws + off);                 off += (size_t)8 * 32 * 12 * 32 * 4; // 384KB
  p.part1 = (float*)(ws + off);              off += (size_t)8 * 32 * 64 * 4;      // 64KB
  p.part2 = (float*)(ws + off);              off += (size_t)8 * 32 * 128 * 4;     // 128KB
  p.wa1b = (unsigned short*)(ws + off);      off += (size_t)NH * NH * 2;          // 2MB
  p.wexb = (unsigned short*)(ws + off);

  // counters/slots must start at 0 each call (monotonic within a call)
  hipMemsetAsync(d_ws, 0, 4096 + (size_t)8 * WPG * SLOTSTRIDE * 4, stream);
  decoder_persistent<<<dim3(256), dim3(256), 0, stream>>>(p);
}